// Round 10
// baseline (523.576 us; speedup 1.0000x reference)
//
#include <hip/hip_runtime.h>
#include <hip/hip_bf16.h>

#define D_IN  128
#define D_HID 512
#define D_OUT 128

typedef short bf16x8 __attribute__((ext_vector_type(8)));
typedef float f32x4  __attribute__((ext_vector_type(4)));
typedef float f32x2  __attribute__((ext_vector_type(2)));

__device__ __forceinline__ unsigned short f2bf(float f) {
    union { __hip_bfloat16 h; unsigned short u; } x;
    x.h = __float2bfloat16(f);
    return x.u;
}

// ---------------- CSR build ----------------
__global__ void hist_k(const int* __restrict__ dst, int E, int* __restrict__ cnt) {
    int e = blockIdx.x * 256 + threadIdx.x;
    if (e < E) atomicAdd(&cnt[dst[e]], 1);
}

// single-block sequential-chunk scan: replaces scan_block + scan_sums + add_off
__global__ __launch_bounds__(1024)
void scan_k(const int* __restrict__ cnt, int* __restrict__ rowptr, int n) {
    __shared__ int sd[1024];
    __shared__ int base;
    const int t = threadIdx.x;
    if (t == 0) { base = 0; rowptr[0] = 0; }
    __syncthreads();
    for (int start = 0; start < n; start += 1024) {
        const int i = start + t;
        int v = (i < n) ? cnt[i] : 0;
        sd[t] = v;
        __syncthreads();
        for (int off = 1; off < 1024; off <<= 1) {
            int x = (t >= off) ? sd[t - off] : 0;
            __syncthreads();
            sd[t] += x;
            __syncthreads();
        }
        if (i < n) rowptr[i + 1] = base + sd[t];
        __syncthreads();                 // all base reads done
        if (t == 0) base += sd[1023];
        __syncthreads();                 // base updated before next chunk
    }
}

__global__ void fill_k(const int* __restrict__ src, const int* __restrict__ dst, int E,
                       const int* __restrict__ rowptr, int* __restrict__ cursor,
                       int* __restrict__ colb) {
    int e = blockIdx.x * 256 + threadIdx.x;
    if (e < E) {
        int d = dst[e];
        int pos = rowptr[d] + atomicAdd(&cursor[d], 1);
        colb[pos] = src[e];
    }
}

// ---------------- fused prep: x->bf16+fp8, W1c, W2c, WLc converts ----------------
__global__ __launch_bounds__(256)
void prep_k(const float* __restrict__ x, unsigned short* __restrict__ A1,
            unsigned char* __restrict__ X8,
            const float* __restrict__ w1r, const float* __restrict__ w1l,
            unsigned short* __restrict__ W1c,
            const float* __restrict__ w2r, const float* __restrict__ w2l,
            unsigned short* __restrict__ W2c,
            const float* __restrict__ wlin, unsigned short* __restrict__ WLc, int N) {
    const int b = blockIdx.x, t = threadIdx.x;
    if (b < 512) {                       // W1c row b = [w1_r | w1_l], 256 cols
        float v = (t < 128) ? w1r[b * 128 + t] : w1l[b * 128 + (t - 128)];
        W1c[b * 256 + t] = f2bf(v);
    } else if (b < 1024) {               // W2c row j = [w2_r | w2_l], 1024 cols
        const int j = b - 512;
        for (int c = t; c < 1024; c += 256) {
            float v = (c < 512) ? w2r[j * 512 + c] : w2l[j * 512 + (c - 512)];
            W2c[j * 1024 + c] = f2bf(v);
        }
    } else if (b < 1280) {               // WLc flat 128*512
        const int i = (b - 1024) * 256 + t;
        WLc[i] = f2bf(wlin[i]);
    } else {                             // x: 2 nodes per block
        const int node = (b - 1280) * 2 + (t >> 7);
        if (node < N) {
            const int c = t & 127;
            float v = x[(long)node * 128 + c];
            A1[(long)node * 256 + c] = f2bf(v);
            int q = __builtin_amdgcn_cvt_pk_fp8_f32(v, v, 0, false);
            X8[(long)node * 128 + c] = (unsigned char)(q & 0xff);
        }
    }
}

// ---------------- aggregation (mean over in-neighbors) ----------------
__global__ __launch_bounds__(256)
void agg1_k(const unsigned char* __restrict__ X8, const int* __restrict__ rowptr,
            const int* __restrict__ colb, unsigned short* __restrict__ A1, int N) {
    const int node = blockIdx.x * 4 + (threadIdx.x >> 6);
    if (node >= N) return;
    const int l = threadIdx.x & 63;
    const int half = l >> 5;
    const int c = (l & 31) * 4;
    const int s = rowptr[node], e = rowptr[node + 1];
    float a0 = 0.f, a1 = 0.f, a2 = 0.f, a3 = 0.f;
    auto accum = [&](unsigned int v) {
        f32x2 p;
        p = __builtin_amdgcn_cvt_pk_f32_fp8((int)v, false); a0 += p[0]; a1 += p[1];
        p = __builtin_amdgcn_cvt_pk_f32_fp8((int)v, true);  a2 += p[0]; a3 += p[1];
    };
    int j = s + half;
    for (; j + 6 < e; j += 8) {
        const int sn0 = colb[j], sn1 = colb[j + 2], sn2 = colb[j + 4], sn3 = colb[j + 6];
        const unsigned int v0 = *(const unsigned int*)(X8 + (long)sn0 * 128 + c);
        const unsigned int v1 = *(const unsigned int*)(X8 + (long)sn1 * 128 + c);
        const unsigned int v2 = *(const unsigned int*)(X8 + (long)sn2 * 128 + c);
        const unsigned int v3 = *(const unsigned int*)(X8 + (long)sn3 * 128 + c);
        accum(v0); accum(v1); accum(v2); accum(v3);
    }
    for (; j < e; j += 2) {
        const unsigned int v0 = *(const unsigned int*)(X8 + (long)colb[j] * 128 + c);
        accum(v0);
    }
    a0 += __shfl_down(a0, 32);
    a1 += __shfl_down(a1, 32);
    a2 += __shfl_down(a2, 32);
    a3 += __shfl_down(a3, 32);
    if (half == 0) {
        const int deg = e - s;
        const float inv = 1.0f / (float)(deg > 0 ? deg : 1);
        ushort4 o;
        o.x = f2bf(a0 * inv);
        o.y = f2bf(a1 * inv);
        o.z = f2bf(a2 * inv);
        o.w = f2bf(a3 * inv);
        *(ushort4*)(A1 + (long)node * 256 + 128 + c) = o;
    }
}

__device__ __forceinline__ void acc_fp8x8(float* acc, unsigned int lo, unsigned int hi) {
    f32x2 p;
    p = __builtin_amdgcn_cvt_pk_f32_fp8((int)lo, false); acc[0] += p[0]; acc[1] += p[1];
    p = __builtin_amdgcn_cvt_pk_f32_fp8((int)lo, true);  acc[2] += p[0]; acc[3] += p[1];
    p = __builtin_amdgcn_cvt_pk_f32_fp8((int)hi, false); acc[4] += p[0]; acc[5] += p[1];
    p = __builtin_amdgcn_cvt_pk_f32_fp8((int)hi, true);  acc[6] += p[0]; acc[7] += p[1];
}

__global__ __launch_bounds__(256)
void agg2_k(const unsigned char* __restrict__ H1q, const int* __restrict__ rowptr,
            const int* __restrict__ colb, unsigned short* __restrict__ A2w, int N) {
    const int node = blockIdx.x * 4 + (threadIdx.x >> 6);
    if (node >= N) return;
    const int l = threadIdx.x & 63;
    const int s = rowptr[node], e = rowptr[node + 1];
    float acc[8] = {};
    int j = s;
    for (; j + 3 < e; j += 4) {
        const int sn0 = colb[j], sn1 = colb[j + 1], sn2 = colb[j + 2], sn3 = colb[j + 3];
        const uint2 v0 = *(const uint2*)(H1q + (long)sn0 * 512 + l * 8);
        const uint2 v1 = *(const uint2*)(H1q + (long)sn1 * 512 + l * 8);
        const uint2 v2 = *(const uint2*)(H1q + (long)sn2 * 512 + l * 8);
        const uint2 v3 = *(const uint2*)(H1q + (long)sn3 * 512 + l * 8);
        acc_fp8x8(acc, v0.x, v0.y);
        acc_fp8x8(acc, v1.x, v1.y);
        acc_fp8x8(acc, v2.x, v2.y);
        acc_fp8x8(acc, v3.x, v3.y);
    }
    for (; j < e; ++j) {
        const uint2 v0 = *(const uint2*)(H1q + (long)colb[j] * 512 + l * 8);
        acc_fp8x8(acc, v0.x, v0.y);
    }
    const int deg = e - s;
    const float inv = 1.0f / (float)(deg > 0 ? deg : 1);
    uint4 o;
    o.x = (unsigned int)f2bf(acc[0] * inv) | ((unsigned int)f2bf(acc[1] * inv) << 16);
    o.y = (unsigned int)f2bf(acc[2] * inv) | ((unsigned int)f2bf(acc[3] * inv) << 16);
    o.z = (unsigned int)f2bf(acc[4] * inv) | ((unsigned int)f2bf(acc[5] * inv) << 16);
    o.w = (unsigned int)f2bf(acc[6] * inv) | ((unsigned int)f2bf(acc[7] * inv) << 16);
    *(uint4*)(A2w + (long)node * 1024 + 512 + l * 8) = o;
}

// ---------------- bf16 MFMA GEMM (128x128): dbuf, vmcnt(4), 3 blocks/CU -----
// Hoisted staging pointers (bump +32/iter), K-loop unrolled x2 so LDS buffer
// bases are compile-time, precomputed LDS read offsets — minimal per-iter VALU.
template <int NCT>
__global__ __launch_bounds__(256, 3)
void gemm_bt(const unsigned short* __restrict__ A, const unsigned short* __restrict__ W,
             const float* __restrict__ bias, int K, int ldc, int Mstore, int nRT,
             unsigned short* __restrict__ Cb, float* __restrict__ Cf,
             unsigned char* __restrict__ Cq, int relu) {
    __shared__ unsigned short lds[16384];  // 2 x 16 KiB
    const int per8 = gridDim.x >> 3;
    const int b = blockIdx.x;
    const int unit = (b & 7) * per8 + (b >> 3);
    if (unit >= nRT * NCT) return;
    const int rt = unit / NCT;
    const int ct = unit % NCT;
    const long bm = (long)rt * 128;
    const long bn = (long)ct * 128;

    const int tid  = threadIdx.x;
    const int lane = tid & 63;
    const int wave = tid >> 6;
    const int wm = (wave >> 1) * 64;
    const int wn = (wave & 1) * 64;
    const int stgRow = lane >> 2;
    const int stgCol = ((lane & 3) ^ ((lane >> 3) & 3)) * 8;
    const int fr = lane & 15;
    const int fq = lane >> 4;
    const int rdSwz = (fq ^ ((fr >> 1) & 3)) * 8;

    // hoisted staging pointers + LDS write offsets (j = wave*4+i)
    const unsigned short* gp[4];
    int wrOff[4];
#pragma unroll
    for (int i = 0; i < 4; ++i) {
        const int j = wave * 4 + i;
        gp[i] = (j < 8 ? A + (bm + j * 16 + stgRow) * (long)K
                       : W + (bn + (j - 8) * 16 + stgRow) * (long)K) + stgCol;
        wrOff[i] = j * 512 + lane * 8;
    }
    // hoisted LDS read offsets
    int rdA[4], rdB[4];
#pragma unroll
    for (int t = 0; t < 4; ++t) {
        rdA[t] = (wm + t * 16 + fr) * 32 + rdSwz;
        rdB[t] = 4096 + (wn + t * 16 + fr) * 32 + rdSwz;
    }

    f32x4 acc[4][4] = {};

    auto stage = [&](const int bufbase) {
#pragma unroll
        for (int i = 0; i < 4; ++i) {
            __builtin_amdgcn_global_load_lds(
                (const __attribute__((address_space(1))) void*)gp[i],
                (__attribute__((address_space(3))) void*)(lds + bufbase + wrOff[i]),
                16, 0, 0);
            gp[i] += 32;
        }
    };
    auto compute = [&](const unsigned short* base) {
        bf16x8 af[4], bfr[4];
#pragma unroll
        for (int t = 0; t < 4; ++t) {
            af[t]  = *(const bf16x8*)(base + rdA[t]);
            bfr[t] = *(const bf16x8*)(base + rdB[t]);
        }
#pragma unroll
        for (int mt = 0; mt < 4; ++mt)
#pragma unroll
            for (int nt = 0; nt < 4; ++nt)
                acc[mt][nt] = __builtin_amdgcn_mfma_f32_16x16x32_bf16(
                    af[mt], bfr[nt], acc[mt][nt], 0, 0, 0);
    };

    const int NK = K >> 5;  // even for all layers (8/32/16)
    stage(0);
    for (int ki = 0; ki < NK; ki += 2) {
        if (ki + 1 < NK) { stage(8192); __builtin_amdgcn_s_waitcnt(0x0F74); }
        else             {              __builtin_amdgcn_s_waitcnt(0x0F70); }
        __builtin_amdgcn_s_barrier();
        compute(lds);
        __builtin_amdgcn_s_waitcnt(0xC07F);
        __builtin_amdgcn_sched_barrier(0);
        __builtin_amdgcn_s_barrier();
        if (ki + 1 >= NK) break;

        if (ki + 2 < NK) { stage(0); __builtin_amdgcn_s_waitcnt(0x0F74); }
        else             {           __builtin_amdgcn_s_waitcnt(0x0F70); }
        __builtin_amdgcn_s_barrier();
        compute(lds + 8192);
        __builtin_amdgcn_s_waitcnt(0xC07F);
        __builtin_amdgcn_sched_barrier(0);
        __builtin_amdgcn_s_barrier();
    }

#pragma unroll
    for (int mt = 0; mt < 4; ++mt) {
#pragma unroll
        for (int nt = 0; nt < 4; ++nt) {
            const long colg = bn + wn + nt * 16 + fr;
            const float bv = bias[colg];
#pragma unroll
            for (int r = 0; r < 4; ++r) {
                const long rowg = bm + wm + mt * 16 + fq * 4 + r;
                if (rowg < Mstore) {
                    float v = acc[mt][nt][r] + bv;
                    if (relu) v = fmaxf(v, 0.0f);
                    const long idx = rowg * (long)ldc + colg;
                    if (Cf) Cf[idx] = v;
                    else    Cb[idx] = f2bf(v);
                    if (Cq) {
                        int q = __builtin_amdgcn_cvt_pk_fp8_f32(v, v, 0, false);
                        Cq[rowg * 512 + colg] = (unsigned char)(q & 0xff);
                    }
                }
            }
        }
    }
}

extern "C" void kernel_launch(void* const* d_in, const int* in_sizes, int n_in,
                              void* d_out, int out_size, void* d_ws, size_t ws_size,
                              hipStream_t stream) {
    const float* x     = (const float*)d_in[0];
    const int*   ei    = (const int*)d_in[1];
    const float* w1_l  = (const float*)d_in[2];
    const float* w1_r  = (const float*)d_in[3];
    const float* b1    = (const float*)d_in[4];
    const float* w2_l  = (const float*)d_in[5];
    const float* w2_r  = (const float*)d_in[6];
    const float* b2    = (const float*)d_in[7];
    const float* w_lin = (const float*)d_in[8];
    const float* b_lin = (const float*)d_in[9];
    float* out = (float*)d_out;

    const int N = in_sizes[0] / D_IN;   // 50000
    const int E = in_sizes[1] / 2;      // 800000
    const int Mpad = (N + 127) & ~127;  // 50048
    const int nRT = Mpad / 128;         // 391
    const int* src = ei;
    const int* dst = ei + E;

    size_t off = 0;
    auto carve = [&](size_t bytes) {
        char* p = (char*)d_ws + off;
        off += (bytes + 511) & ~(size_t)511;
        return (void*)p;
    };
    int* cnt    = (int*)carve((size_t)N * 4);
    int* cursor = (int*)carve((size_t)N * 4);
    int* rowptr = (int*)carve((size_t)(N + 1) * 4);
    int* colb   = (int*)carve((size_t)E * 4);
    unsigned short* A1  = (unsigned short*)carve((size_t)Mpad * 256 * 2);   // [x | mean1]
    unsigned short* A2  = (unsigned short*)carve((size_t)Mpad * 1024 * 2);  // [h1 | mean2]
    unsigned short* H2  = (unsigned short*)carve((size_t)Mpad * 512 * 2);
    unsigned char*  H1q = (unsigned char*)carve((size_t)Mpad * 512);        // fp8 h1 copy
    unsigned char*  X8  = (unsigned char*)carve((size_t)N * 128);           // fp8 x copy
    unsigned short* W1c = (unsigned short*)carve((size_t)512 * 256 * 2);    // [w1_r | w1_l]
    unsigned short* W2c = (unsigned short*)carve((size_t)512 * 1024 * 2);   // [w2_r | w2_l]
    unsigned short* WLc = (unsigned short*)carve((size_t)128 * 512 * 2);

    hipMemsetAsync(cnt, 0, ((size_t)N * 4 + 511 & ~(size_t)511) + (size_t)N * 4, stream);

    hist_k<<<(E + 255) / 256, 256, 0, stream>>>(dst, E, cnt);
    scan_k<<<1, 1024, 0, stream>>>(cnt, rowptr, N);
    fill_k<<<(E + 255) / 256, 256, 0, stream>>>(src, dst, E, rowptr, cursor, colb);

    const int gprep = 1280 + (N + 1) / 2;  // 512 W1c + 512 W2c + 256 WLc + x blocks
    prep_k<<<gprep, 256, 0, stream>>>(x, A1, X8, w1_r, w1_l, W1c,
                                      w2_r, w2_l, W2c, w_lin, WLc, N);

    const int gagg = (N + 3) / 4;
    agg1_k<<<gagg, 256, 0, stream>>>(X8, rowptr, colb, A1, N);

    const int G12 = ((nRT * 4 + 7) & ~7);  // 1568
    const int G3  = ((nRT * 1 + 7) & ~7);  // 392
    // layer 1: h1 = relu(A1 @ W1c^T + b1) -> A2 cols [0,512) (bf16) + H1q (fp8)
    gemm_bt<4><<<G12, 256, 0, stream>>>(A1, W1c, b1, 256, 1024, Mpad, nRT, A2, nullptr, H1q, 1);
    agg2_k<<<gagg, 256, 0, stream>>>(H1q, rowptr, colb, A2, N);
    // layer 2: h2 = relu(A2 @ W2c^T + b2) -> H2
    gemm_bt<4><<<G12, 256, 0, stream>>>(A2, W2c, b2, 1024, 512, Mpad, nRT, H2, nullptr, nullptr, 1);
    // head: out = H2 @ WLc^T + b_lin (fp32 store, masked to N rows)
    gemm_bt<1><<<G3, 256, 0, stream>>>(H2, WLc, b_lin, 512, 128, N, nRT, nullptr, out, nullptr, 0);
}

// Round 11
// 429.686 us; speedup vs baseline: 1.2185x; 1.2185x over previous
//
#include <hip/hip_runtime.h>
#include <hip/hip_bf16.h>

#define D_IN  128
#define D_HID 512
#define D_OUT 128

typedef short bf16x8 __attribute__((ext_vector_type(8)));
typedef float f32x4  __attribute__((ext_vector_type(4)));
typedef float f32x2  __attribute__((ext_vector_type(2)));

__device__ __forceinline__ unsigned short f2bf(float f) {
    union { __hip_bfloat16 h; unsigned short u; } x;
    x.h = __float2bfloat16(f);
    return x.u;
}

// ---------------- CSR build (parallel 3-kernel scan — R9 version) ----------------
__global__ void hist_k(const int* __restrict__ dst, int E, int* __restrict__ cnt) {
    int e = blockIdx.x * 256 + threadIdx.x;
    if (e < E) atomicAdd(&cnt[dst[e]], 1);
}

__global__ void scan_block_k(const int* __restrict__ cnt, int* __restrict__ rowptr,
                             int* __restrict__ bsum, int n) {
    __shared__ int sd[256];
    int t = threadIdx.x;
    int i = blockIdx.x * 256 + t;
    int v = (i < n) ? cnt[i] : 0;
    sd[t] = v;
    __syncthreads();
    for (int off = 1; off < 256; off <<= 1) {
        int x = (t >= off) ? sd[t - off] : 0;
        __syncthreads();
        sd[t] += x;
        __syncthreads();
    }
    if (i < n) rowptr[i + 1] = sd[t];
    if (t == 255) bsum[blockIdx.x] = sd[255];
    if (i == 0) rowptr[0] = 0;
}

__global__ void scan_sums_k(int* __restrict__ bsum, int nb) {
    __shared__ int sd[256];
    int t = threadIdx.x;
    int v = (t < nb) ? bsum[t] : 0;
    sd[t] = v;
    __syncthreads();
    for (int off = 1; off < 256; off <<= 1) {
        int x = (t >= off) ? sd[t - off] : 0;
        __syncthreads();
        sd[t] += x;
        __syncthreads();
    }
    if (t < nb) bsum[t] = sd[t] - v;   // exclusive
}

__global__ void add_off_k(int* __restrict__ rowptr, const int* __restrict__ bsum, int n) {
    int i = blockIdx.x * 256 + threadIdx.x;
    if (i < n) rowptr[i + 1] += bsum[blockIdx.x];
}

__global__ void fill_k(const int* __restrict__ src, const int* __restrict__ dst, int E,
                       const int* __restrict__ rowptr, int* __restrict__ cursor,
                       int* __restrict__ colb) {
    int e = blockIdx.x * 256 + threadIdx.x;
    if (e < E) {
        int d = dst[e];
        int pos = rowptr[d] + atomicAdd(&cursor[d], 1);
        colb[pos] = src[e];
    }
}

// ---------------- fused prep: x->bf16+fp8, W1c, W2c, WLc converts ----------------
__global__ __launch_bounds__(256)
void prep_k(const float* __restrict__ x, unsigned short* __restrict__ A1,
            unsigned char* __restrict__ X8,
            const float* __restrict__ w1r, const float* __restrict__ w1l,
            unsigned short* __restrict__ W1c,
            const float* __restrict__ w2r, const float* __restrict__ w2l,
            unsigned short* __restrict__ W2c,
            const float* __restrict__ wlin, unsigned short* __restrict__ WLc, int N) {
    const int b = blockIdx.x, t = threadIdx.x;
    if (b < 512) {                       // W1c row b = [w1_r | w1_l], 256 cols
        float v = (t < 128) ? w1r[b * 128 + t] : w1l[b * 128 + (t - 128)];
        W1c[b * 256 + t] = f2bf(v);
    } else if (b < 1024) {               // W2c row j = [w2_r | w2_l], 1024 cols
        const int j = b - 512;
        for (int c = t; c < 1024; c += 256) {
            float v = (c < 512) ? w2r[j * 512 + c] : w2l[j * 512 + (c - 512)];
            W2c[j * 1024 + c] = f2bf(v);
        }
    } else if (b < 1280) {               // WLc flat 128*512
        const int i = (b - 1024) * 256 + t;
        WLc[i] = f2bf(wlin[i]);
    } else {                             // x: 2 nodes per block
        const int node = (b - 1280) * 2 + (t >> 7);
        if (node < N) {
            const int c = t & 127;
            float v = x[(long)node * 128 + c];
            A1[(long)node * 256 + c] = f2bf(v);
            int q = __builtin_amdgcn_cvt_pk_fp8_f32(v, v, 0, false);
            X8[(long)node * 128 + c] = (unsigned char)(q & 0xff);
        }
    }
}

// ---------------- aggregation (mean over in-neighbors) ----------------
__global__ __launch_bounds__(256)
void agg1_k(const unsigned char* __restrict__ X8, const int* __restrict__ rowptr,
            const int* __restrict__ colb, unsigned short* __restrict__ A1, int N) {
    const int node = blockIdx.x * 4 + (threadIdx.x >> 6);
    if (node >= N) return;
    const int l = threadIdx.x & 63;
    const int half = l >> 5;
    const int c = (l & 31) * 4;
    const int s = rowptr[node], e = rowptr[node + 1];
    float a0 = 0.f, a1 = 0.f, a2 = 0.f, a3 = 0.f;
    auto accum = [&](unsigned int v) {
        f32x2 p;
        p = __builtin_amdgcn_cvt_pk_f32_fp8((int)v, false); a0 += p[0]; a1 += p[1];
        p = __builtin_amdgcn_cvt_pk_f32_fp8((int)v, true);  a2 += p[0]; a3 += p[1];
    };
    int j = s + half;
    for (; j + 6 < e; j += 8) {
        const int sn0 = colb[j], sn1 = colb[j + 2], sn2 = colb[j + 4], sn3 = colb[j + 6];
        const unsigned int v0 = *(const unsigned int*)(X8 + (long)sn0 * 128 + c);
        const unsigned int v1 = *(const unsigned int*)(X8 + (long)sn1 * 128 + c);
        const unsigned int v2 = *(const unsigned int*)(X8 + (long)sn2 * 128 + c);
        const unsigned int v3 = *(const unsigned int*)(X8 + (long)sn3 * 128 + c);
        accum(v0); accum(v1); accum(v2); accum(v3);
    }
    for (; j < e; j += 2) {
        const unsigned int v0 = *(const unsigned int*)(X8 + (long)colb[j] * 128 + c);
        accum(v0);
    }
    a0 += __shfl_down(a0, 32);
    a1 += __shfl_down(a1, 32);
    a2 += __shfl_down(a2, 32);
    a3 += __shfl_down(a3, 32);
    if (half == 0) {
        const int deg = e - s;
        const float inv = 1.0f / (float)(deg > 0 ? deg : 1);
        ushort4 o;
        o.x = f2bf(a0 * inv);
        o.y = f2bf(a1 * inv);
        o.z = f2bf(a2 * inv);
        o.w = f2bf(a3 * inv);
        *(ushort4*)(A1 + (long)node * 256 + 128 + c) = o;
    }
}

__device__ __forceinline__ void acc_fp8x8(float* acc, unsigned int lo, unsigned int hi) {
    f32x2 p;
    p = __builtin_amdgcn_cvt_pk_f32_fp8((int)lo, false); acc[0] += p[0]; acc[1] += p[1];
    p = __builtin_amdgcn_cvt_pk_f32_fp8((int)lo, true);  acc[2] += p[0]; acc[3] += p[1];
    p = __builtin_amdgcn_cvt_pk_f32_fp8((int)hi, false); acc[4] += p[0]; acc[5] += p[1];
    p = __builtin_amdgcn_cvt_pk_f32_fp8((int)hi, true);  acc[6] += p[0]; acc[7] += p[1];
}

// agg2: fp8 gather (512 B rows); lane l owns cols 8l..8l+7; 8 independent chains.
__global__ __launch_bounds__(256)
void agg2_k(const unsigned char* __restrict__ H1q, const int* __restrict__ rowptr,
            const int* __restrict__ colb, unsigned short* __restrict__ A2w, int N) {
    const int node = blockIdx.x * 4 + (threadIdx.x >> 6);
    if (node >= N) return;
    const int l = threadIdx.x & 63;
    const int s = rowptr[node], e = rowptr[node + 1];
    float acc[8] = {};
    int j = s;
    for (; j + 7 < e; j += 8) {
        uint2 v[8];
#pragma unroll
        for (int q = 0; q < 8; ++q)
            v[q] = *(const uint2*)(H1q + (long)colb[j + q] * 512 + l * 8);
#pragma unroll
        for (int q = 0; q < 8; ++q)
            acc_fp8x8(acc, v[q].x, v[q].y);
    }
    for (; j < e; ++j) {
        const uint2 v0 = *(const uint2*)(H1q + (long)colb[j] * 512 + l * 8);
        acc_fp8x8(acc, v0.x, v0.y);
    }
    const int deg = e - s;
    const float inv = 1.0f / (float)(deg > 0 ? deg : 1);
    uint4 o;
    o.x = (unsigned int)f2bf(acc[0] * inv) | ((unsigned int)f2bf(acc[1] * inv) << 16);
    o.y = (unsigned int)f2bf(acc[2] * inv) | ((unsigned int)f2bf(acc[3] * inv) << 16);
    o.z = (unsigned int)f2bf(acc[4] * inv) | ((unsigned int)f2bf(acc[5] * inv) << 16);
    o.w = (unsigned int)f2bf(acc[6] * inv) | ((unsigned int)f2bf(acc[7] * inv) << 16);
    *(uint4*)(A2w + (long)node * 1024 + 512 + l * 8) = o;
}

// ---------------- bf16 MFMA GEMM (128x128): dbuf, vmcnt(4), 3 blocks/CU -----
// (R9 version — best measured: VGPR 56, occupancy 32%. R10's pointer-hoist
// variant raised VGPR to 84 and regressed; VALU here is hidden under MFMA.)
template <int NCT>
__global__ __launch_bounds__(256, 3)
void gemm_bt(const unsigned short* __restrict__ A, const unsigned short* __restrict__ W,
             const float* __restrict__ bias, int K, int ldc, int Mstore, int nRT,
             unsigned short* __restrict__ Cb, float* __restrict__ Cf,
             unsigned char* __restrict__ Cq, int relu) {
    __shared__ unsigned short lds[16384];  // 2 x 16 KiB
    const int per8 = gridDim.x >> 3;
    const int b = blockIdx.x;
    const int unit = (b & 7) * per8 + (b >> 3);
    if (unit >= nRT * NCT) return;
    const int rt = unit / NCT;
    const int ct = unit % NCT;
    const long bm = (long)rt * 128;
    const long bn = (long)ct * 128;

    const int tid  = threadIdx.x;
    const int lane = tid & 63;
    const int wave = tid >> 6;
    const int wm = (wave >> 1) * 64;
    const int wn = (wave & 1) * 64;
    const int stgRow = lane >> 2;
    const int stgCol = ((lane & 3) ^ ((lane >> 3) & 3)) * 8;
    const int fr = lane & 15;
    const int fq = lane >> 4;
    const int rdSwz = (fq ^ ((fr >> 1) & 3)) * 8;

    f32x4 acc[4][4] = {};

    auto stage = [&](int buf, int k0) {
#pragma unroll
        for (int i = 0; i < 4; ++i) {
            int j = wave * 4 + i;
            const unsigned short* g;
            if (j < 8) g = A + (bm + j * 16 + stgRow) * (long)K + k0 + stgCol;
            else       g = W + (bn + (j - 8) * 16 + stgRow) * (long)K + k0 + stgCol;
            __builtin_amdgcn_global_load_lds(
                (const __attribute__((address_space(1))) void*)g,
                (__attribute__((address_space(3))) void*)(lds + buf * 8192 + j * 512 + lane * 8),
                16, 0, 0);
        }
    };

    const int NK = K >> 5;
    stage(0, 0);
    for (int ki = 0; ki < NK; ++ki) {
        const int cur = ki & 1;
        if (ki + 1 < NK) {
            stage(cur ^ 1, (ki + 1) << 5);
            __builtin_amdgcn_s_waitcnt(0x0F74);  // vmcnt(4)
        } else {
            __builtin_amdgcn_s_waitcnt(0x0F70);  // vmcnt(0)
        }
        __builtin_amdgcn_s_barrier();

        const unsigned short* base = lds + cur * 8192;
        bf16x8 af[4], bfr[4];
#pragma unroll
        for (int t = 0; t < 4; ++t) {
            af[t]  = *(const bf16x8*)(base +        (wm + t * 16 + fr) * 32 + rdSwz);
            bfr[t] = *(const bf16x8*)(base + 4096 + (wn + t * 16 + fr) * 32 + rdSwz);
        }
#pragma unroll
        for (int mt = 0; mt < 4; ++mt)
#pragma unroll
            for (int nt = 0; nt < 4; ++nt)
                acc[mt][nt] = __builtin_amdgcn_mfma_f32_16x16x32_bf16(
                    af[mt], bfr[nt], acc[mt][nt], 0, 0, 0);

        __builtin_amdgcn_s_waitcnt(0xC07F);      // lgkmcnt(0)
        __builtin_amdgcn_sched_barrier(0);
        __builtin_amdgcn_s_barrier();
    }

#pragma unroll
    for (int mt = 0; mt < 4; ++mt) {
#pragma unroll
        for (int nt = 0; nt < 4; ++nt) {
            const long colg = bn + wn + nt * 16 + fr;
            const float bv = bias[colg];
#pragma unroll
            for (int r = 0; r < 4; ++r) {
                const long rowg = bm + wm + mt * 16 + fq * 4 + r;
                if (rowg < Mstore) {
                    float v = acc[mt][nt][r] + bv;
                    if (relu) v = fmaxf(v, 0.0f);
                    const long idx = rowg * (long)ldc + colg;
                    if (Cf) Cf[idx] = v;
                    else    Cb[idx] = f2bf(v);
                    if (Cq) {
                        int q = __builtin_amdgcn_cvt_pk_fp8_f32(v, v, 0, false);
                        Cq[rowg * 512 + colg] = (unsigned char)(q & 0xff);
                    }
                }
            }
        }
    }
}

extern "C" void kernel_launch(void* const* d_in, const int* in_sizes, int n_in,
                              void* d_out, int out_size, void* d_ws, size_t ws_size,
                              hipStream_t stream) {
    const float* x     = (const float*)d_in[0];
    const int*   ei    = (const int*)d_in[1];
    const float* w1_l  = (const float*)d_in[2];
    const float* w1_r  = (const float*)d_in[3];
    const float* b1    = (const float*)d_in[4];
    const float* w2_l  = (const float*)d_in[5];
    const float* w2_r  = (const float*)d_in[6];
    const float* b2    = (const float*)d_in[7];
    const float* w_lin = (const float*)d_in[8];
    const float* b_lin = (const float*)d_in[9];
    float* out = (float*)d_out;

    const int N = in_sizes[0] / D_IN;   // 50000
    const int E = in_sizes[1] / 2;      // 800000
    const int Mpad = (N + 127) & ~127;  // 50048
    const int nRT = Mpad / 128;         // 391
    const int* src = ei;
    const int* dst = ei + E;

    size_t off = 0;
    auto carve = [&](size_t bytes) {
        char* p = (char*)d_ws + off;
        off += (bytes + 511) & ~(size_t)511;
        return (void*)p;
    };
    int* cnt    = (int*)carve((size_t)N * 4);
    int* cursor = (int*)carve((size_t)N * 4);
    int* rowptr = (int*)carve((size_t)(N + 1) * 4);
    int* bsum   = (int*)carve(256 * 4);
    int* colb   = (int*)carve((size_t)E * 4);
    unsigned short* A1  = (unsigned short*)carve((size_t)Mpad * 256 * 2);   // [x | mean1]
    unsigned short* A2  = (unsigned short*)carve((size_t)Mpad * 1024 * 2);  // [h1 | mean2]
    unsigned short* H2  = (unsigned short*)carve((size_t)Mpad * 512 * 2);
    unsigned char*  H1q = (unsigned char*)carve((size_t)Mpad * 512);        // fp8 h1 copy
    unsigned char*  X8  = (unsigned char*)carve((size_t)N * 128);           // fp8 x copy
    unsigned short* W1c = (unsigned short*)carve((size_t)512 * 256 * 2);    // [w1_r | w1_l]
    unsigned short* W2c = (unsigned short*)carve((size_t)512 * 1024 * 2);   // [w2_r | w2_l]
    unsigned short* WLc = (unsigned short*)carve((size_t)128 * 512 * 2);

    hipMemsetAsync(cnt, 0, ((size_t)N * 4 + 511 & ~(size_t)511) + (size_t)N * 4, stream);

    const int nb = (N + 255) / 256;
    hist_k<<<(E + 255) / 256, 256, 0, stream>>>(dst, E, cnt);
    scan_block_k<<<nb, 256, 0, stream>>>(cnt, rowptr, bsum, N);
    scan_sums_k<<<1, 256, 0, stream>>>(bsum, nb);
    add_off_k<<<nb, 256, 0, stream>>>(rowptr, bsum, N);
    fill_k<<<(E + 255) / 256, 256, 0, stream>>>(src, dst, E, rowptr, cursor, colb);

    const int gprep = 1280 + (N + 1) / 2;
    prep_k<<<gprep, 256, 0, stream>>>(x, A1, X8, w1_r, w1_l, W1c,
                                      w2_r, w2_l, W2c, w_lin, WLc, N);

    const int gagg = (N + 3) / 4;
    agg1_k<<<gagg, 256, 0, stream>>>(X8, rowptr, colb, A1, N);

    const int G12 = ((nRT * 4 + 7) & ~7);  // 1568
    const int G3  = ((nRT * 1 + 7) & ~7);  // 392
    // layer 1: h1 = relu(A1 @ W1c^T + b1) -> A2 cols [0,512) (bf16) + H1q (fp8)
    gemm_bt<4><<<G12, 256, 0, stream>>>(A1, W1c, b1, 256, 1024, Mpad, nRT, A2, nullptr, H1q, 1);
    agg2_k<<<gagg, 256, 0, stream>>>(H1q, rowptr, colb, A2, N);
    // layer 2: h2 = relu(A2 @ W2c^T + b2) -> H2
    gemm_bt<4><<<G12, 256, 0, stream>>>(A2, W2c, b2, 1024, 512, Mpad, nRT, H2, nullptr, nullptr, 1);
    // head: out = H2 @ WLc^T + b_lin (fp32 store, masked to N rows)
    gemm_bt<1><<<G3, 256, 0, stream>>>(H2, WLc, b_lin, 512, 128, N, nRT, nullptr, out, nullptr, 0);
}